// Round 7
// baseline (173.182 us; speedup 1.0000x reference)
//
#include <hip/hip_runtime.h>

constexpr int HD = 128;      // hidden size
constexpr int BROWS = 64;    // rows per bucket == rows per mega-block
constexpr int CAP = 2048;    // LDS sorted-edge capacity per bucket
constexpr int NBMAX = 2048;  // max buckets (N <= 131072)

typedef __attribute__((ext_vector_type(8))) short short8v;  // 8 bf16 (4 VGPR)
typedef __attribute__((ext_vector_type(4))) float f32x4;
typedef __attribute__((ext_vector_type(2))) float f32x2;

__device__ __forceinline__ int rl(int v, int j) {
    return __builtin_amdgcn_readlane(v, j);
}
__device__ __forceinline__ float rlf(int v, int j) {
    return __uint_as_float((unsigned)__builtin_amdgcn_readlane(v, j));
}
__device__ __forceinline__ unsigned f2bf(float f) {  // f32 -> bf16 bits, RNE
    unsigned u = __float_as_uint(f);
    return (u + 0x7fffu + ((u >> 16) & 1u)) >> 16;
}

// meta.x layout: bits[31:26] = local row (0..63), bits[25:8] = col*256 (byte
// offset of the xb row; col < 131072 so col*256 < 2^25), bits[7:0] = 0.
#define META_OFF_MASK 0x03FFFF00

// ---------------------------------------------------------------------------
// prep: three block-ranges in one launch.
//  [0, PB)          : per-row L1 norm of x; pack xb = bf16x2(x * rnorm)
//  [PB, PB+32)      : Wb bf16 pack, B-fragment layout, XOR-swizzled
//  [PB+32, +HB)     : LDS-aggregated bucket histogram; the LAST hist block to
//                     finish also performs the exclusive scan -> bbase/bcursor
// ---------------------------------------------------------------------------
__global__ void prep_kernel(const float* __restrict__ x,
                            unsigned* __restrict__ xb,
                            const float* __restrict__ W,
                            unsigned* __restrict__ Wb,
                            const int* __restrict__ rows,
                            int* __restrict__ bcnt,   // [NB] counts + [NB]=done
                            int* __restrict__ bbase,
                            int* __restrict__ bcursor,
                            int N, int E, int PB, int HB, int NB) {
    int bid = blockIdx.x;
    int tid = threadIdx.x;
    if (bid < PB) {
        int row = bid * 4 + (tid >> 6);
        int lane = tid & 63;
        if (row >= N) return;
        float2 v = *((const float2*)(x + (size_t)row * HD) + lane);
        float s = fabsf(v.x) + fabsf(v.y);
#pragma unroll
        for (int m = 1; m < 64; m <<= 1) s += __shfl_xor(s, m, 64);
        float rn = 1.0f / fmaxf(s, 1e-12f);
        unsigned lo = f2bf(v.x * rn), hi = f2bf(v.y * rn);
        xb[(size_t)row * 64 + lane] = lo | (hi << 16);
    } else if (bid < PB + 32) {
        int t = (bid - PB) * 256 + tid;  // 0..8191 => (col, k2)
        int col = t >> 6, k2 = t & 63;
        float w0 = W[col * HD + 2 * k2];
        float w1 = W[col * HD + 2 * k2 + 1];
        unsigned pk = f2bf(w0) | (f2bf(w1) << 16);
        int byte = (col * 256 + k2 * 4) ^ ((col & 7) << 4);
        *(unsigned*)((char*)Wb + byte) = pk;
    } else {
        __shared__ int lbin[NBMAX];
        __shared__ int aux[256];
        __shared__ int is_last;
        for (int i = tid; i < NBMAX; i += 256) lbin[i] = 0;
        __syncthreads();
        int base = (bid - PB - 32) * 4096;
#pragma unroll 4
        for (int i = 0; i < 16; ++i) {
            int e = base + i * 256 + tid;
            if (e < E) atomicAdd(&lbin[rows[e] >> 6], 1);
        }
        __syncthreads();
        for (int i = tid; i < NB; i += 256) {
            int c = lbin[i];
            if (c) atomicAdd(&bcnt[i], c);
        }
        __threadfence();
        __syncthreads();
        if (tid == 0) is_last = (atomicAdd(&bcnt[NB], 1) == HB - 1);
        __syncthreads();
        if (!is_last) return;
        __threadfence();
        // last hist block: exclusive scan of bcnt[0..NB) -> bbase, bcursor
        int v[8];
        int base8 = tid * 8;
        int s = 0;
#pragma unroll
        for (int i = 0; i < 8; ++i) {
            int idx = base8 + i;
            v[i] = (idx < NB) ? atomicAdd(&bcnt[idx], 0) : 0;  // coherent read
            s += v[i];
        }
        aux[tid] = s;
        __syncthreads();
        for (int off = 1; off < 256; off <<= 1) {
            int add = (tid >= off) ? aux[tid - off] : 0;
            __syncthreads();
            aux[tid] += add;
            __syncthreads();
        }
        int run = aux[tid] - s;
#pragma unroll
        for (int i = 0; i < 8; ++i) {
            int idx = base8 + i;
            if (idx < NB) { bbase[idx] = run; bcursor[idx] = run; }
            run += v[i];
        }
    }
}

// ---------------------------------------------------------------------------
// bscatter: aggregated scatter into bucket-grouped staging.
// Per block: LDS-rank each edge within its bucket, reserve a contiguous
// global range per nonzero bucket (ONE global atomic each), write
// bstage[base+rank] = {packed meta, val}.
// ---------------------------------------------------------------------------
__global__ void __launch_bounds__(512) bscatter_kernel(
    const int* __restrict__ rows, const int* __restrict__ cols,
    const float* __restrict__ vals, int* __restrict__ bcursor,
    int2* __restrict__ bstage, int E, int NB) {
    __shared__ int lbin[NBMAX];
    __shared__ int lbase[NBMAX];
    int tid = threadIdx.x;
    int base = blockIdx.x * 4096;
    for (int i = tid; i < NBMAX; i += 512) lbin[i] = 0;
    __syncthreads();
    int bkt[8], cc[8], vv[8], rk[8];
#pragma unroll
    for (int i = 0; i < 8; ++i) {
        int e = base + i * 512 + tid;
        bkt[i] = -1;
        if (e < E) {
            int r = rows[e];
            cc[i] = (cols[e] << 8) | ((r & 63) << 26);
            vv[i] = __float_as_int(vals[e]);
            bkt[i] = r >> 6;
            rk[i] = atomicAdd(&lbin[bkt[i]], 1);
        }
    }
    __syncthreads();
    for (int i = tid; i < NB; i += 512) {
        int c = lbin[i];
        if (c) lbase[i] = atomicAdd(&bcursor[i], c);
    }
    __syncthreads();
#pragma unroll
    for (int i = 0; i < 8; ++i) {
        if (bkt[i] >= 0)
            bstage[lbase[bkt[i]] + rk[i]] = make_int2(cc[i], vv[i]);
    }
}

// ---------------------------------------------------------------------------
// mega: per 64-row bucket (1024 threads = 16 waves):
//  1. bucket edges -> regs; in-LDS 64-bin counting sort -> local CSR
//  2. gather: each wave accumulates 4 f-rows (pk-f32 FMA, SGPR-base loads)
//  3. f -> bf16 -> swizzled LDS A-tile
//  4. GEMM via mfma_f32_16x16x32_bf16 (wave = 16x32 output tile)
//  5. bias, row-L1 via shfl + LDS float atomics, relu, residual, store
// ---------------------------------------------------------------------------
__global__ void __launch_bounds__(1024) mega_kernel(
    const float* __restrict__ x, const unsigned* __restrict__ xb,
    int2* bstage, const int* __restrict__ bbase, const int* __restrict__ bcnt,
    const unsigned* __restrict__ Wb, const float* __restrict__ bias,
    const float* __restrict__ tsp, float* __restrict__ out, int N) {
    __shared__ char wb_raw[HD * HD * 2];     // 32 KiB bf16 W, B-layout, swz
    __shared__ char fb_raw[BROWS * HD * 2];  // 16 KiB bf16 F, A-layout, swz
    __shared__ int2 sorted[CAP];             // 16 KiB
    __shared__ int lcnt[BROWS], lbeg[BROWS], lcur[BROWS];
    __shared__ float rowsum[BROWS];

    int tid = threadIdx.x;
    int bid = blockIdx.x;
    int bb = bbase[bid];
    int ct = bcnt[bid];

    if (tid < BROWS) lcnt[tid] = 0;

    // phase 1: bucket edges -> registers
    int2 m0 = make_int2(0, 0), m1 = make_int2(0, 0);
    bool e0 = tid < ct, e1 = tid + 1024 < ct;
    if (e0) m0 = bstage[bb + tid];
    if (e1) m1 = bstage[bb + tid + 1024];
    __syncthreads();

    // phase 2: LDS histogram of local rows
    if (e0) atomicAdd(&lcnt[(unsigned)m0.x >> 26], 1);
    if (e1) atomicAdd(&lcnt[(unsigned)m1.x >> 26], 1);
    __syncthreads();

    // phase 3: wave 0 exclusive-scans the 64 counts
    if (tid < 64) {
        int c = lcnt[tid];
        int s = c;
#pragma unroll
        for (int m = 1; m < 64; m <<= 1) {
            int t2 = __shfl_up(s, m, 64);
            if (tid >= m) s += t2;
        }
        lbeg[tid] = s - c;
        lcur[tid] = s - c;
    }
    __syncthreads();

    // phase 4: scatter edges into LDS-sorted local CSR (+ stage Wb)
    if (e0) {
        int p = atomicAdd(&lcur[(unsigned)m0.x >> 26], 1);
        if (p < CAP) sorted[p] = m0; else bstage[bb + p] = m0;
    }
    if (e1) {
        int p = atomicAdd(&lcur[(unsigned)m1.x >> 26], 1);
        if (p < CAP) sorted[p] = m1; else bstage[bb + p] = m1;
    }
    {
        const float4* s4 = (const float4*)Wb;
        float4* d4 = (float4*)wb_raw;
        for (int i = tid; i < HD * HD * 2 / 16; i += 1024) d4[i] = s4[i];
    }
    __syncthreads();

    int lane = tid & 63;
    int wid = tid >> 6;
    float ts = tsp[0];
    const char* xbl = (const char*)xb + (lane << 2);

    // ---- gather: accumulate 4 f-rows (f32x2) per wave ----
    float a0[4], a1[4];
#pragma unroll
    for (int rr = 0; rr < 4; ++rr) {
        int lr = wid * 4 + rr;
        int beg = lbeg[lr], cnt = lcnt[lr];
        f32x2 pq0 = {0.f, 0.f}, pq1 = {0.f, 0.f};
        for (int jb = 0; jb < cnt; jb += 64) {
            int rem = cnt - jb;
            if (rem > 64) rem = 64;
            int2 meta = make_int2(0, 0);
            if (lane < rem) {
                int pidx = beg + jb + lane;
                meta = (pidx < CAP) ? sorted[pidx] : bstage[bb + pidx];
            }
            int j = 0;
            for (; j + 4 <= rem; j += 4) {
                int o0 = rl(meta.x, j) & META_OFF_MASK;
                int o1 = rl(meta.x, j + 1) & META_OFF_MASK;
                int o2 = rl(meta.x, j + 2) & META_OFF_MASK;
                int o3 = rl(meta.x, j + 3) & META_OFF_MASK;
                float s0 = rlf(meta.y, j), s1 = rlf(meta.y, j + 1);
                float s2 = rlf(meta.y, j + 2), s3 = rlf(meta.y, j + 3);
                unsigned u0 = *(const unsigned*)(xbl + o0);
                unsigned u1 = *(const unsigned*)(xbl + o1);
                unsigned u2 = *(const unsigned*)(xbl + o2);
                unsigned u3 = *(const unsigned*)(xbl + o3);
                f32x2 xv0 = {__uint_as_float(u0 << 16),
                             __uint_as_float(u0 & 0xffff0000u)};
                f32x2 xv1 = {__uint_as_float(u1 << 16),
                             __uint_as_float(u1 & 0xffff0000u)};
                f32x2 xv2 = {__uint_as_float(u2 << 16),
                             __uint_as_float(u2 & 0xffff0000u)};
                f32x2 xv3 = {__uint_as_float(u3 << 16),
                             __uint_as_float(u3 & 0xffff0000u)};
                pq0 += xv0 * s0;
                pq1 += xv1 * s1;
                pq0 += xv2 * s2;
                pq1 += xv3 * s3;
            }
            for (; j < rem; ++j) {
                int o0 = rl(meta.x, j) & META_OFF_MASK;
                float s0 = rlf(meta.y, j);
                unsigned u0 = *(const unsigned*)(xbl + o0);
                f32x2 xv0 = {__uint_as_float(u0 << 16),
                             __uint_as_float(u0 & 0xffff0000u)};
                pq0 += xv0 * s0;
            }
        }
        a0[rr] = pq0.x + pq1.x;
        a1[rr] = pq0.y + pq1.y;
    }

    // ---- phase C: f -> bf16 swizzled LDS A-tile; init rowsum ----
#pragma unroll
    for (int rr = 0; rr < 4; ++rr) {
        int row = wid * 4 + rr;  // local row
        unsigned pk = f2bf(a0[rr]) | (f2bf(a1[rr]) << 16);
        int byte = (row * 256 + lane * 4) ^ ((row & 7) << 4);
        *(unsigned*)(fb_raw + byte) = pk;
    }
    if (tid < BROWS) rowsum[tid] = 0.f;
    __syncthreads();

    // ---- MFMA GEMM: wave -> 16-row x 32-col output tile ----
    int rt = wid >> 2;        // row-tile 0..3
    int ct0 = (wid & 3) * 2;  // first col-tile (of 8)
    int c = lane & 15;
    int kg = lane >> 4;
    int arow = rt * 16 + c;
    int bcol0 = ct0 * 16 + c;
    int bcol1 = bcol0 + 16;
    f32x4 acc0 = {0.f, 0.f, 0.f, 0.f}, acc1 = {0.f, 0.f, 0.f, 0.f};
#pragma unroll
    for (int kk = 0; kk < 4; ++kk) {
        int ka = kg * 16 + kk * 64;  // byte offset of this lane's k-chunk
        short8v af = *(const short8v*)(fb_raw +
                                       ((arow * 256 + ka) ^ ((arow & 7) << 4)));
        short8v bf0 = *(const short8v*)(wb_raw +
                                        ((bcol0 * 256 + ka) ^ ((bcol0 & 7) << 4)));
        short8v bf1 = *(const short8v*)(wb_raw +
                                        ((bcol1 * 256 + ka) ^ ((bcol1 & 7) << 4)));
        acc0 = __builtin_amdgcn_mfma_f32_16x16x32_bf16(af, bf0, acc0, 0, 0, 0);
        acc1 = __builtin_amdgcn_mfma_f32_16x16x32_bf16(af, bf1, acc1, 0, 0, 0);
    }

    // ---- epilogue: bias, row-L1 reduce, normalize, relu, residual ----
    float bias0 = bias[bcol0];
    float bias1 = bias[bcol1];
    float g0r[4], g1r[4];
#pragma unroll
    for (int r = 0; r < 4; ++r) {
        float v0 = acc0[r] + bias0;
        float v1 = acc1[r] + bias1;
        g0r[r] = v0;
        g1r[r] = v1;
        float s = fabsf(v0) + fabsf(v1);
        s += __shfl_xor(s, 1, 64);
        s += __shfl_xor(s, 2, 64);
        s += __shfl_xor(s, 4, 64);
        s += __shfl_xor(s, 8, 64);
        if (c == 0) atomicAdd(&rowsum[rt * 16 + kg * 4 + r], s);
    }
    __syncthreads();
#pragma unroll
    for (int r = 0; r < 4; ++r) {
        int lrow = rt * 16 + kg * 4 + r;
        int row = bid * BROWS + lrow;
        if (row < N) {
            float rn = 1.0f / fmaxf(rowsum[lrow], 1e-12f);
            float G0 = fmaxf(g0r[r] * rn, 0.f);
            float G1 = fmaxf(g1r[r] * rn, 0.f);
            float x0 = x[(size_t)row * HD + bcol0];
            float x1 = x[(size_t)row * HD + bcol1];
            out[(size_t)row * HD + bcol0] = fmaf(ts, G0, x0);
            out[(size_t)row * HD + bcol1] = fmaf(ts, G1, x1);
        }
    }
}

extern "C" void kernel_launch(void* const* d_in, const int* in_sizes, int n_in,
                              void* d_out, int out_size, void* d_ws,
                              size_t ws_size, hipStream_t stream) {
    const float* x = (const float*)d_in[0];
    const int* Ar = (const int*)d_in[1];
    const int* Ac = (const int*)d_in[2];
    const float* Av = (const float*)d_in[3];
    const float* W = (const float*)d_in[4];
    const float* b = (const float*)d_in[5];
    const float* ts = (const float*)d_in[6];

    int N = in_sizes[0] / HD;
    int E = in_sizes[1];
    float* out = (float*)d_out;

    int NB = (N + BROWS - 1) / BROWS;

    char* ws = (char*)d_ws;
    size_t o = 0;
    auto take = [&](size_t bytes) {
        void* p = ws + o;
        o += (bytes + 511) & ~(size_t)511;
        return p;
    };
    int* bcnt = (int*)take((size_t)(NB + 1) * 4);  // +1: done-counter
    int* bbase = (int*)take((size_t)NB * 4);
    int* bcursor = (int*)take((size_t)NB * 4);
    unsigned* Wb = (unsigned*)take((size_t)HD * HD * 2);
    unsigned* xb = (unsigned*)take((size_t)N * 64 * 4);
    int2* bstage = (int2*)take((size_t)E * 8);

    hipMemsetAsync(bcnt, 0, (size_t)(NB + 1) * 4, stream);

    int PB = (N + 3) / 4;
    int HB = (E + 4095) / 4096;
    prep_kernel<<<PB + 32 + HB, 256, 0, stream>>>(x, xb, W, Wb, Ar, bcnt, bbase,
                                                  bcursor, N, E, PB, HB, NB);
    bscatter_kernel<<<HB, 512, 0, stream>>>(Ar, Ac, Av, bcursor, bstage, E, NB);
    mega_kernel<<<NB, 1024, 0, stream>>>(x, xb, bstage, bbase, bcnt, Wb, b, ts,
                                         out, N);
}